// Round 3
// baseline (102.279 us; speedup 1.0000x reference)
//
#include <hip/hip_runtime.h>
#include <hip/hip_bf16.h>

#define N_PTS 20000
#define NSAMP 32
#define CIN 64
#define COUT 128
#define M_ROWS (N_PTS * NSAMP)   // 640000 rows
#define TILES (M_ROWS / 64)      // 10000 64-row tiles
#define K1_BLOCKS 1024
#define K1_WAVES (K1_BLOCKS * 4) // 4096
#define BN_EPS 1e-5f

typedef __attribute__((ext_vector_type(8))) short short8v;
typedef __attribute__((ext_vector_type(4))) float f32x4;

// float -> bf16 bits, round-to-nearest-even
__device__ inline short bf16_of(float f) {
    unsigned u = __float_as_uint(f);
    u = (u + 0x7FFFu + ((u >> 16) & 1u)) >> 16;
    return (short)u;
}

// ---------------------------------------------------------------------------
// Kernel 1: stream F once, compute x = F*W^T per 64-row tile via MFMA, and
// accumulate per-channel sum(x), sum(x^2) in f32.  Per-block partials (1KB).
// A-slot holds F[row][k(slot)], B-slot holds W[d][k(slot)] with the SAME slot
// mapping -> any hardware k-permutation cancels.  Only the verified C/D
// layout (col = lane&15, row = (lane>>4)*4 + reg) is relied upon.
// ---------------------------------------------------------------------------
__global__ __launch_bounds__(256) void k1_stats(const float* __restrict__ F,
                                                const float* __restrict__ W,
                                                float* __restrict__ SxP,
                                                float* __restrict__ Sx2P) {
    const int tid = threadIdx.x;
    const int wid = tid >> 6;
    const int lane = tid & 63;
    const int g = lane >> 4;
    const int i = lane & 15;
    const int gw = blockIdx.x * 4 + wid;

    // W fragments (B operand), register-resident: b[t][kk]
    short8v b[8][2];
#pragma unroll
    for (int t = 0; t < 8; ++t)
#pragma unroll
        for (int kk = 0; kk < 2; ++kk) {
            const float* wp = W + (t * 16 + i) * 64 + kk * 32 + g * 8;
            short8v fr;
#pragma unroll
            for (int r = 0; r < 8; ++r) fr[r] = bf16_of(wp[r]);
            b[t][kk] = fr;
        }

    float sx[8], sx2[8];
#pragma unroll
    for (int t = 0; t < 8; ++t) { sx[t] = 0.f; sx2[t] = 0.f; }
    const f32x4 Z = {0.f, 0.f, 0.f, 0.f};

    for (int tile = gw; tile < TILES; tile += K1_WAVES) {
        const float* base = F + (size_t)tile * 4096;
#pragma unroll
        for (int mt = 0; mt < 4; ++mt) {
            // A fragments: 8 consecutive floats per slot -> dwordx4 pairs
            short8v a[2];
#pragma unroll
            for (int kk = 0; kk < 2; ++kk) {
                const float* fp = base + (mt * 16 + i) * 64 + kk * 32 + g * 8;
                short8v fr;
#pragma unroll
                for (int r = 0; r < 8; ++r) fr[r] = bf16_of(fp[r]);
                a[kk] = fr;
            }
#pragma unroll
            for (int t = 0; t < 8; ++t) {
                f32x4 acc = __builtin_amdgcn_mfma_f32_16x16x32_bf16(
                    a[0], b[t][0], Z, 0, 0, 0);
                acc = __builtin_amdgcn_mfma_f32_16x16x32_bf16(
                    a[1], b[t][1], acc, 0, 0, 0);
#pragma unroll
                for (int r = 0; r < 4; ++r) {
                    float v = acc[r];
                    sx[t] += v;
                    sx2[t] = fmaf(v, v, sx2[t]);
                }
            }
        }
    }

    // reduce the 4 lane-groups (g) holding the same channel d = t*16 + i
#pragma unroll
    for (int t = 0; t < 8; ++t) {
        sx[t] += __shfl_xor(sx[t], 16);
        sx[t] += __shfl_xor(sx[t], 32);
        sx2[t] += __shfl_xor(sx2[t], 16);
        sx2[t] += __shfl_xor(sx2[t], 32);
    }

    // block-level reduction across the 4 waves via small LDS buffer
    __shared__ float sL[2][4][128];
    if (lane < 16) {
#pragma unroll
        for (int t = 0; t < 8; ++t) {
            sL[0][wid][t * 16 + lane] = sx[t];
            sL[1][wid][t * 16 + lane] = sx2[t];
        }
    }
    __syncthreads();
    if (tid < 256) {
        int arr = tid >> 7;
        int d = tid & 127;
        float s = sL[arr][0][d] + sL[arr][1][d] + sL[arr][2][d] + sL[arr][3][d];
        (arr ? Sx2P : SxP)[(size_t)blockIdx.x * 128 + d] = s;
    }
}

// ---------------------------------------------------------------------------
// Finalize: reduce 1024 block partials per channel, compute BN scale/shift.
// 8 blocks x 256 threads; fully coalesced reads of SxP/Sx2P.
// ---------------------------------------------------------------------------
__global__ __launch_bounds__(256) void k_fin(const float* __restrict__ SxP,
                                             const float* __restrict__ Sx2P,
                                             const float* __restrict__ gamma,
                                             const float* __restrict__ beta,
                                             float* __restrict__ scale,
                                             float* __restrict__ shift) {
    const int tid = threadIdx.x;
    const int d0 = blockIdx.x * 16;
    const int dsel = tid & 15;
    const int bgrp = tid >> 4;  // 0..15

    float s1 = 0.f, s2 = 0.f;
#pragma unroll 8
    for (int bb = 0; bb < 64; ++bb) {
        int bk = bb * 16 + bgrp;
        s1 += SxP[(size_t)bk * 128 + d0 + dsel];
        s2 += Sx2P[(size_t)bk * 128 + d0 + dsel];
    }
    __shared__ float r1[16][16], r2[16][16];
    r1[bgrp][dsel] = s1;
    r2[bgrp][dsel] = s2;
    __syncthreads();
    if (tid < 16) {
        float t1 = 0.f, t2 = 0.f;
#pragma unroll
        for (int j = 0; j < 16; ++j) { t1 += r1[j][tid]; t2 += r2[j][tid]; }
        const float invM = 1.f / (float)M_ROWS;
        int d = d0 + tid;
        float mu = t1 * invM;
        float var = t2 * invM - mu * mu;
        float rs = rsqrtf(var + BN_EPS);
        float sc = gamma[d] * rs;
        scale[d] = sc;
        shift[d] = beta[d] - mu * sc;
    }
}

// ---------------------------------------------------------------------------
// Kernel 2: fused GEMM (bf16 MFMA) + BN affine + ReLU + geo-weighted masked
// mean-pool.  One wave per 4 points; W fragments register-resident; per-wave
// geo buffer in LDS; DS-only sched pin so VMEM/MFMA can overlap freely.
// ---------------------------------------------------------------------------
__global__ __launch_bounds__(256) void k2_main(const float* __restrict__ F,
                                               const float* __restrict__ coords,
                                               const float* __restrict__ centers,
                                               const int* __restrict__ mask,
                                               const float* __restrict__ W,
                                               const float* __restrict__ scale,
                                               const float* __restrict__ shift,
                                               float* __restrict__ out) {
    const int tid = threadIdx.x;
    const int wid = tid >> 6;
    const int lane = tid & 63;
    const int g = lane >> 4;
    const int i = lane & 15;
    const int n_base = (blockIdx.x * 4 + wid) * 4;

    // B fragments (W^T), register-resident
    short8v b[8][2];
#pragma unroll
    for (int t = 0; t < 8; ++t)
#pragma unroll
        for (int kk = 0; kk < 2; ++kk) {
            const float* wp = W + (t * 16 + i) * 64 + kk * 32 + g * 8;
            short8v fr;
#pragma unroll
            for (int r = 0; r < 8; ++r) fr[r] = bf16_of(wp[r]);
            b[t][kk] = fr;
        }
    float sc[8], sh[8];
#pragma unroll
    for (int t = 0; t < 8; ++t) {
        sc[t] = scale[t * 16 + i];
        sh[t] = shift[t * 16 + i];
    }

    __shared__ float geoM[4][32][4];  // per-wave private
    const f32x4 Z = {0.f, 0.f, 0.f, 0.f};

    for (int it = 0; it < 4; ++it) {
        const int n = n_base + it;

        // A fragments first: contiguous 8-float runs -> dwordx4 loads,
        // issued early so they are in flight during the geo phase.
        short8v a[2][2];
#pragma unroll
        for (int mt = 0; mt < 2; ++mt)
#pragma unroll
            for (int kk = 0; kk < 2; ++kk) {
                const float* fp =
                    F + ((size_t)n * NSAMP + mt * 16 + i) * 64 + kk * 32 + g * 8;
                short8v fr;
#pragma unroll
                for (int r = 0; r < 8; ++r) fr[r] = bf16_of(fp[r]);
                a[mt][kk] = fr;
            }

        // geo phase: lanes 0..31 each own one neighbor s
        float m = 0.f;
        if (lane < 32) {
            const int s = lane;
            const float* cp = coords + ((size_t)n * NSAMP + s) * 3;
            float r0 = cp[0] - centers[n * 4 + 1];
            float r1 = cp[1] - centers[n * 4 + 2];
            float r2 = cp[2] - centers[n * 4 + 3];
            float dist = r0 * r0 + r1 * r1 + r2 * r2;
            m = (float)mask[n * NSAMP + s];
            float4 gm = make_float4(r0 * 10.f * m, r1 * 10.f * m,
                                    r2 * 5.f * m, dist * (1.f / 0.06f) * m);
            *(float4*)&geoM[wid][s][0] = gm;
        }
        float den = m;
        for (int k = 1; k <= 32; k <<= 1) den += __shfl_xor(den, k);
        float inv_den = 1.f / fmaxf(den, 1.f);

        // pin only DS ops (write above vs reads below); ALU/VMEM/MFMA may cross
        __builtin_amdgcn_sched_barrier(0x7F);

        // per-lane geo weights for the 8 rows this lane's C covers
        float gv[2][4];
        const int j0 = i & 3;  // d % 4
#pragma unroll
        for (int mt = 0; mt < 2; ++mt)
#pragma unroll
            for (int r = 0; r < 4; ++r)
                gv[mt][r] = geoM[wid][mt * 16 + g * 4 + r][j0];

#pragma unroll
        for (int t = 0; t < 8; ++t) {
            float nump = 0.f;
#pragma unroll
            for (int mt = 0; mt < 2; ++mt) {
                f32x4 acc = __builtin_amdgcn_mfma_f32_16x16x32_bf16(
                    a[mt][0], b[t][0], Z, 0, 0, 0);
                acc = __builtin_amdgcn_mfma_f32_16x16x32_bf16(
                    a[mt][1], b[t][1], acc, 0, 0, 0);
#pragma unroll
                for (int r = 0; r < 4; ++r) {
                    float v = fmaf(acc[r], sc[t], sh[t]);
                    v = fmaxf(v, 0.f);
                    nump = fmaf(v, gv[mt][r], nump);
                }
            }
            nump += __shfl_xor(nump, 16);
            nump += __shfl_xor(nump, 32);
            if (lane < 16)
                out[(size_t)n * COUT + t * 16 + lane] = nump * inv_den;
        }
    }
}

// ---------------------------------------------------------------------------
extern "C" void kernel_launch(void* const* d_in, const int* in_sizes, int n_in,
                              void* d_out, int out_size, void* d_ws, size_t ws_size,
                              hipStream_t stream) {
    const float* F = (const float*)d_in[0];
    const float* coords = (const float*)d_in[1];
    const float* centers = (const float*)d_in[2];
    const int* mask = (const int*)d_in[3];
    const float* W = (const float*)d_in[4];
    const float* gamma = (const float*)d_in[5];
    const float* beta = (const float*)d_in[6];
    float* out = (float*)d_out;

    float* wsf = (float*)d_ws;
    float* scale = wsf;                         // 128
    float* shift = wsf + 128;                   // 128
    float* SxP = wsf + 256;                     // 1024*128
    float* Sx2P = SxP + (size_t)K1_BLOCKS * 128;  // 1024*128

    k1_stats<<<K1_BLOCKS, 256, 0, stream>>>(F, W, SxP, Sx2P);
    k_fin<<<8, 256, 0, stream>>>(SxP, Sx2P, gamma, beta, scale, shift);
    k2_main<<<1250, 256, 0, stream>>>(F, coords, centers, mask, W, scale, shift, out);
}